// Round 1
// baseline (902.670 us; speedup 1.0000x reference)
//
#include <hip/hip_runtime.h>
#include <math.h>

#define NPTS 1024
#define S_   512
#define T_   8
#define K_   32
#define B_   2

// ---------------------------------------------------------------------------
// Kernel 1: farthest point sampling on frame 0 of each batch.
// 1 block per batch, 64 threads (1 wave). Each lane owns 16 points in regs.
// Matches jax scan: emit `far` BEFORE update; argmax = first occurrence.
// ---------------------------------------------------------------------------
__global__ void fps_kernel(const float* __restrict__ xyz, int* __restrict__ fidx)
{
    int b    = blockIdx.x;
    int lane = threadIdx.x;
    __shared__ float sx[NPTS], sy[NPTS], sz[NPTS];
    const float* bx = xyz + (size_t)b * (T_ * 3 * NPTS);   // frame 0 of batch b
    float px[16], py[16], pz[16], mind[16];
#pragma unroll
    for (int j = 0; j < 16; ++j) {
        int n = j * 64 + lane;
        float x = bx[n], y = bx[NPTS + n], z = bx[2 * NPTS + n];
        px[j] = x; py[j] = y; pz[j] = z;
        sx[n] = x; sy[n] = y; sz[n] = z;
        mind[j] = 1e10f;
    }
    __syncthreads();
    int far = 0;
    for (int it = 0; it < S_; ++it) {
        if (lane == 0) fidx[b * S_ + it] = far;
        float cx = sx[far], cy = sy[far], cz = sz[far];
        // packed key: high 32 = dist bits (monotonic for >=0), low 32 = 1023-n
        // -> u64 max == (max dist, tie: smallest n)
        unsigned long long key = 0ull;
#pragma unroll
        for (int j = 0; j < 16; ++j) {
            float dx = __fsub_rn(px[j], cx);
            float dy = __fsub_rn(py[j], cy);
            float dz = __fsub_rn(pz[j], cz);
            float d  = __fmaf_rn(dz, dz, __fmaf_rn(dy, dy, __fmul_rn(dx, dx)));
            float mn = fminf(mind[j], d);
            mind[j] = mn;
            unsigned long long cand =
                (((unsigned long long)__float_as_uint(mn)) << 32) |
                (unsigned long long)(1023u - (unsigned)(j * 64 + lane));
            key = (cand > key) ? cand : key;
        }
#pragma unroll
        for (int off = 1; off < 64; off <<= 1) {
            unsigned long long ok = __shfl_xor(key, off);
            key = (ok > key) ? ok : key;
        }
        far = 1023 - (int)(key & 0xFFFFFFFFull);
    }
}

// ---------------------------------------------------------------------------
// Kernel 2: ball query per (bt, s). 1 wave per block.
// sq via (A + B) - 2*dot, fma-chain dot (matches gemm-style contraction).
// First 32 valid indices ascending via ballot + prefix popcount; pad w/ first.
// Also writes new_xyz to d_out part 0 and to ws for the gather in conv1.
// ---------------------------------------------------------------------------
__global__ void ballquery_kernel(const float* __restrict__ xyz,
                                 const int* __restrict__ fidx,
                                 int* __restrict__ gidx,
                                 float* __restrict__ newxyz,
                                 float* __restrict__ out0)
{
    int s    = blockIdx.x;
    int bt   = blockIdx.y;
    int b    = bt >> 3;
    int lane = threadIdx.x;
    const float* bx = xyz + (size_t)bt * 3 * NPTS;
    int fid = fidx[b * S_ + s];
    float nx = bx[fid], ny = bx[NPTS + fid], nz = bx[2 * NPTS + fid];
    if (lane < 3) {
        float vv = (lane == 0) ? nx : ((lane == 1) ? ny : nz);
        out0[(bt * 3 + lane) * S_ + s]   = vv;   // [B,t,3,S]
        newxyz[(bt * S_ + s) * 3 + lane] = vv;
    }
    float A = __fmaf_rn(nz, nz, __fmaf_rn(ny, ny, __fmul_rn(nx, nx)));
    const float R2 = (float)(0.2 * 0.2);
    int* g = gidx + (size_t)(bt * S_ + s) * K_;
    int count = 0, firstIdx = -1;
    for (int j = 0; j < 16; ++j) {
        if (count >= K_) break;
        int n = j * 64 + lane;
        float x = bx[n], y = bx[NPTS + n], z = bx[2 * NPTS + n];
        float Bn = __fmaf_rn(z, z, __fmaf_rn(y, y, __fmul_rn(x, x)));
        float C  = __fmaf_rn(nz, z, __fmaf_rn(ny, y, __fmul_rn(nx, x)));
        float sq = __fsub_rn(__fadd_rn(A, Bn), __fmul_rn(2.0f, C));
        bool valid = !(sq > R2);
        unsigned long long mb = __ballot(valid);
        if (valid) {
            int pos = count + __popcll(mb & ((1ull << lane) - 1ull));
            if (pos < K_) g[pos] = n;
        }
        if (firstIdx < 0 && mb) firstIdx = j * 64 + (__ffsll((long long)mb) - 1);
        count += __popcll(mb);
    }
    if (count < K_) {
        for (int p = count + lane; p < K_; p += 64) g[p] = firstIdx;
    }
}

// ---------------------------------------------------------------------------
// Conv[1,4,1] + BN + ReLU (+ optional fused gather on input / maxpool on out).
// grid (S, B, coTiles). block 256. Each block: one (b,s), 64 output channels.
// LDS: x tile [CI][8][32] + weight tile [64][CI][4]  (<=137 KB, 1 block/CU).
// Thread: k = tid&31, cg = tid>>5; computes acc[8 tt][8 co].
// ---------------------------------------------------------------------------
template <int CI, bool GATHER, bool POOL>
__global__ __launch_bounds__(256) void conv_kernel(
    const float* __restrict__ xin,
    const float* __restrict__ xyz, const float* __restrict__ points,
    const int* __restrict__ gidx, const float* __restrict__ newxyz,
    const float* __restrict__ w,  const float* __restrict__ bb,
    const float* __restrict__ gg, const float* __restrict__ be,
    const float* __restrict__ mm, const float* __restrict__ vv,
    float* __restrict__ out)
{
    __shared__ float xs[CI * 256];
    __shared__ float wsh[64 * CI * 4];
    int s = blockIdx.x, b = blockIdx.y;
    int co_base = blockIdx.z * 64;
    int tid = threadIdx.x;

    for (int i = tid; i < 64 * CI * 4; i += 256)
        wsh[i] = w[(size_t)co_base * CI * 4 + i];

    if (GATHER) {
        int bt0 = b * T_;
        for (int e = tid; e < CI * 256; e += 256) {
            int ci = e >> 8; int tk = e & 255; int tt = tk >> 5; int k = tk & 31;
            int bt = bt0 + tt;
            int idx = gidx[(size_t)(bt * S_ + s) * K_ + k];
            float val;
            if (ci < 3)
                val = xyz[(size_t)(bt * 3 + ci) * NPTS + idx]
                      - newxyz[(bt * S_ + s) * 3 + ci];
            else
                val = points[(size_t)(bt * 64 + (ci - 3)) * NPTS + idx];
            xs[e] = val;
        }
    } else {
        for (int e = tid; e < CI * 256; e += 256) {
            int ci = e >> 8; int tk = e & 255;
            xs[e] = xin[((size_t)(b * CI + ci) * S_ + s) * 256 + tk];
        }
    }
    __syncthreads();

    int k = tid & 31, cg = tid >> 5;
    float acc[8][8];
#pragma unroll
    for (int tt = 0; tt < 8; ++tt)
#pragma unroll
        for (int j = 0; j < 8; ++j) acc[tt][j] = 0.0f;

    for (int ci = 0; ci < CI; ++ci) {
        float xr[8];
#pragma unroll
        for (int p = 0; p < 8; ++p) xr[p] = xs[(ci * 8 + p) * 32 + k];
#pragma unroll
        for (int dt = 0; dt < 4; ++dt) {
            float wv[8];
#pragma unroll
            for (int j = 0; j < 8; ++j)
                wv[j] = wsh[((cg * 8 + j) * CI + ci) * 4 + dt];
#pragma unroll
            for (int tt = 0; tt < 8; ++tt) {
                int xt = tt + dt - 1;
                if (xt < 0 || xt > 7) continue;
                float xv = xr[xt];
#pragma unroll
                for (int j = 0; j < 8; ++j)
                    acc[tt][j] = __builtin_fmaf(wv[j], xv, acc[tt][j]);
            }
        }
    }

#pragma unroll
    for (int j = 0; j < 8; ++j) {
        int co = co_base + cg * 8 + j;
        float bias = bb[co], mu = mm[co], beta = be[co];
        float sc = gg[co] / sqrtf(vv[co] + 1e-5f);
        if (POOL) {
            float mx[8];
#pragma unroll
            for (int tt = 0; tt < 8; ++tt) {
                float val = fmaxf((acc[tt][j] + bias - mu) * sc + beta, 0.0f);
#pragma unroll
                for (int off = 1; off < 32; off <<= 1)
                    val = fmaxf(val, __shfl_xor(val, off));
                mx[tt] = val;
            }
            if (k == 0) {
#pragma unroll
                for (int tt = 0; tt < 8; ++tt)
                    out[((size_t)(b * T_ + tt) * 128 + co) * S_ + s] = mx[tt];
            }
        } else {
#pragma unroll
            for (int tt = 0; tt < 8; ++tt) {
                float val = fmaxf((acc[tt][j] + bias - mu) * sc + beta, 0.0f);
                out[((size_t)(b * 64 + co) * S_ + s) * 256 + tt * 32 + k] = val;
            }
        }
    }
}

// ---------------------------------------------------------------------------
extern "C" void kernel_launch(void* const* d_in, const int* in_sizes, int n_in,
                              void* d_out, int out_size, void* d_ws, size_t ws_size,
                              hipStream_t stream)
{
    (void)in_sizes; (void)n_in; (void)out_size; (void)ws_size;
    const float* xyz    = (const float*)d_in[0];
    const float* points = (const float*)d_in[1];
    const float* w0 = (const float*)d_in[2];
    const float* b0 = (const float*)d_in[3];
    const float* g0 = (const float*)d_in[4];
    const float* be0 = (const float*)d_in[5];
    const float* m0 = (const float*)d_in[6];
    const float* v0 = (const float*)d_in[7];
    const float* w1 = (const float*)d_in[8];
    const float* b1 = (const float*)d_in[9];
    const float* g1 = (const float*)d_in[10];
    const float* be1 = (const float*)d_in[11];
    const float* m1 = (const float*)d_in[12];
    const float* v1 = (const float*)d_in[13];
    const float* w2 = (const float*)d_in[14];
    const float* b2 = (const float*)d_in[15];
    const float* g2 = (const float*)d_in[16];
    const float* be2 = (const float*)d_in[17];
    const float* m2 = (const float*)d_in[18];
    const float* v2 = (const float*)d_in[19];

    float* out = (float*)d_out;
    char* ws = (char*)d_ws;
    int*   fidx = (int*)ws;                                   // 2*512*4      = 4 KB
    int*   gidx = (int*)(ws + 4096);                          // 16*512*32*4  = 1 MB
    float* nxyz = (float*)(ws + 4096 + 16 * 512 * 32 * 4);    // 16*512*3*4   = 96 KB
    float* actA = (float*)(ws + (size_t)(2 * 1024 * 1024));           // 64 MB
    float* actB = (float*)(ws + (size_t)(2 * 1024 * 1024) + 67108864);// 64 MB

    fps_kernel<<<B_, 64, 0, stream>>>(xyz, fidx);
    ballquery_kernel<<<dim3(S_, B_ * T_), 64, 0, stream>>>(xyz, fidx, gidx, nxyz, out);

    conv_kernel<67, true, false><<<dim3(S_, B_, 1), 256, 0, stream>>>(
        nullptr, xyz, points, gidx, nxyz, w0, b0, g0, be0, m0, v0, actA);
    conv_kernel<64, false, false><<<dim3(S_, B_, 1), 256, 0, stream>>>(
        actA, nullptr, nullptr, nullptr, nullptr, w1, b1, g1, be1, m1, v1, actB);
    conv_kernel<64, false, true><<<dim3(S_, B_, 2), 256, 0, stream>>>(
        actB, nullptr, nullptr, nullptr, nullptr, w2, b2, g2, be2, m2, v2,
        out + (size_t)B_ * T_ * 3 * S_);
}

// Round 3
// 600.053 us; speedup vs baseline: 1.5043x; 1.5043x over previous
//
#include <hip/hip_runtime.h>
#include <math.h>

#define NPTS 1024
#define S_   512
#define T_   8
#define K_   32
#define B_   2

typedef short bf16x8 __attribute__((ext_vector_type(8)));
typedef short short4v __attribute__((ext_vector_type(4)));
typedef float f32x4 __attribute__((ext_vector_type(4)));

static __device__ __forceinline__ short f2bf(float f) {
    unsigned u = __float_as_uint(f);
    unsigned r = (u + 0x7FFFu + ((u >> 16) & 1u)) >> 16;   // RNE
    return (short)r;
}

// ---------------------------------------------------------------------------
// Kernel 1: farthest point sampling on frame 0 of each batch (unchanged).
// ---------------------------------------------------------------------------
__global__ void fps_kernel(const float* __restrict__ xyz, int* __restrict__ fidx)
{
    int b    = blockIdx.x;
    int lane = threadIdx.x;
    __shared__ float sx[NPTS], sy[NPTS], sz[NPTS];
    const float* bx = xyz + (size_t)b * (T_ * 3 * NPTS);   // frame 0 of batch b
    float px[16], py[16], pz[16], mind[16];
#pragma unroll
    for (int j = 0; j < 16; ++j) {
        int n = j * 64 + lane;
        float x = bx[n], y = bx[NPTS + n], z = bx[2 * NPTS + n];
        px[j] = x; py[j] = y; pz[j] = z;
        sx[n] = x; sy[n] = y; sz[n] = z;
        mind[j] = 1e10f;
    }
    __syncthreads();
    int far = 0;
    for (int it = 0; it < S_; ++it) {
        if (lane == 0) fidx[b * S_ + it] = far;
        float cx = sx[far], cy = sy[far], cz = sz[far];
        unsigned long long key = 0ull;
#pragma unroll
        for (int j = 0; j < 16; ++j) {
            float dx = __fsub_rn(px[j], cx);
            float dy = __fsub_rn(py[j], cy);
            float dz = __fsub_rn(pz[j], cz);
            float d  = __fmaf_rn(dz, dz, __fmaf_rn(dy, dy, __fmul_rn(dx, dx)));
            float mn = fminf(mind[j], d);
            mind[j] = mn;
            unsigned long long cand =
                (((unsigned long long)__float_as_uint(mn)) << 32) |
                (unsigned long long)(1023u - (unsigned)(j * 64 + lane));
            key = (cand > key) ? cand : key;
        }
#pragma unroll
        for (int off = 1; off < 64; off <<= 1) {
            unsigned long long ok = __shfl_xor(key, off);
            key = (ok > key) ? ok : key;
        }
        far = 1023 - (int)(key & 0xFFFFFFFFull);
    }
}

// ---------------------------------------------------------------------------
// Kernel 2: ball query per (bt, s). 1 wave per block (unchanged).
// ---------------------------------------------------------------------------
__global__ void ballquery_kernel(const float* __restrict__ xyz,
                                 const int* __restrict__ fidx,
                                 int* __restrict__ gidx,
                                 float* __restrict__ newxyz,
                                 float* __restrict__ out0)
{
    int s    = blockIdx.x;
    int bt   = blockIdx.y;
    int b    = bt >> 3;
    int lane = threadIdx.x;
    const float* bx = xyz + (size_t)bt * 3 * NPTS;
    int fid = fidx[b * S_ + s];
    float nx = bx[fid], ny = bx[NPTS + fid], nz = bx[2 * NPTS + fid];
    if (lane < 3) {
        float vv = (lane == 0) ? nx : ((lane == 1) ? ny : nz);
        out0[(bt * 3 + lane) * S_ + s]   = vv;   // [B,t,3,S]
        newxyz[(bt * S_ + s) * 3 + lane] = vv;
    }
    float A = __fmaf_rn(nz, nz, __fmaf_rn(ny, ny, __fmul_rn(nx, nx)));
    const float R2 = (float)(0.2 * 0.2);
    int* g = gidx + (size_t)(bt * S_ + s) * K_;
    int count = 0, firstIdx = -1;
    for (int j = 0; j < 16; ++j) {
        if (count >= K_) break;
        int n = j * 64 + lane;
        float x = bx[n], y = bx[NPTS + n], z = bx[2 * NPTS + n];
        float Bn = __fmaf_rn(z, z, __fmaf_rn(y, y, __fmul_rn(x, x)));
        float C  = __fmaf_rn(nz, z, __fmaf_rn(ny, y, __fmul_rn(nx, x)));
        float sq = __fsub_rn(__fadd_rn(A, Bn), __fmul_rn(2.0f, C));
        bool valid = !(sq > R2);
        unsigned long long mb = __ballot(valid);
        if (valid) {
            int pos = count + __popcll(mb & ((1ull << lane) - 1ull));
            if (pos < K_) g[pos] = n;
        }
        if (firstIdx < 0 && mb) firstIdx = j * 64 + (__ffsll((long long)mb) - 1);
        count += __popcll(mb);
    }
    if (count < K_) {
        for (int p = count + lane; p < K_; p += 64) g[p] = firstIdx;
    }
}

// ---------------------------------------------------------------------------
// MFMA conv: per-(b,s) GEMM  out[64 co][256 pos] = sum_dt W_dt * Xshift_dt.
// grid (S, B, coTiles), block 256 (4 waves). Wave w owns co rows [16w,16w+16).
// LDS: wsh[4 dt][64 co][CIp] bf16, xs[256 col][CIp] bf16.
// dt handled as whole-fragment column offset (dt-1)*32, compile-time masked.
// A frag: lane -> m=l&15, k=(l>>4)*8+e ; B frag: n=l&15, k=(l>>4)*8+e ;
// D frag: n=l&15, m=(l>>4)*4+j  (m89-verified C/D layout).
// ---------------------------------------------------------------------------
template <int CI, int CIp, int NK, bool GATHER, bool POOL>
__global__ __launch_bounds__(256) void conv_mfma(
    const short* __restrict__ actIn,
    const float* __restrict__ xyz, const float* __restrict__ points,
    const int* __restrict__ gidx, const float* __restrict__ newxyz,
    const float* __restrict__ w,  const float* __restrict__ bb,
    const float* __restrict__ gg, const float* __restrict__ be,
    const float* __restrict__ mm, const float* __restrict__ vv,
    short* __restrict__ actOut, float* __restrict__ outPool)
{
    __shared__ __align__(16) short wsh[4 * 64 * CIp];
    __shared__ __align__(16) short xs[256 * CIp];
    int s = blockIdx.x, b = blockIdx.y;
    int co_base = blockIdx.z * 64;
    int tid = threadIdx.x;

    // ---- stage weights (fp32 -> bf16), layout [dt][co][ci], zero-pad ci ----
    for (int e = tid; e < 4 * 64 * CIp; e += 256) {
        int dt = e / (64 * CIp);
        int rem = e - dt * (64 * CIp);
        int co = rem / CIp;
        int ci = rem - co * CIp;
        float val = (ci < CI) ? w[(((size_t)(co_base + co)) * CI + ci) * 4 + dt] : 0.0f;
        wsh[e] = f2bf(val);
    }

    // ---- stage x tile: xs[col][ci] bf16, col = t*32 + k ----
    {
        int col = tid;
        short* xrow = &xs[col * CIp];
        if (GATHER) {
            int k = col & 31, tt = col >> 5;
            int bt = b * T_ + tt;
            int idx = gidx[((size_t)bt * S_ + s) * K_ + k];
            const float* nxp = &newxyz[((size_t)bt * S_ + s) * 3];
#pragma unroll
            for (int ci = 0; ci < 3; ++ci)
                xrow[ci] = f2bf(xyz[(size_t)(bt * 3 + ci) * NPTS + idx] - nxp[ci]);
            for (int ci = 0; ci < 64; ++ci)
                xrow[3 + ci] = f2bf(points[((size_t)bt * 64 + ci) * NPTS + idx]);
            for (int ci = 67; ci < CIp; ++ci) xrow[ci] = 0;
        } else {
            const short* src = actIn + (((size_t)b * S_ + s) * 256 + col) * 64;
#pragma unroll
            for (int c = 0; c < 8; ++c)   // 8 x 16B = 64 bf16 channels
                ((int4*)xrow)[c] = ((const int4*)src)[c];
            for (int ci = 64; ci < CIp; ++ci) xrow[ci] = 0;
        }
    }
    __syncthreads();

    int lane = tid & 63;
    int wv   = tid >> 6;          // wave id 0..3 -> co stripe
    int l16  = lane & 15;
    int lq   = lane >> 4;

    f32x4 acc[16];
#pragma unroll
    for (int nb = 0; nb < 16; ++nb) acc[nb] = (f32x4){0.f, 0.f, 0.f, 0.f};

#pragma unroll
    for (int ks = 0; ks < NK; ++ks) {
        bf16x8 afr[4];
#pragma unroll
        for (int dt = 0; dt < 4; ++dt)
            afr[dt] = *(const bf16x8*)&wsh[(dt * 64 + wv * 16 + l16) * CIp + ks * 32 + lq * 8];
        bf16x8 bfr[16];
#pragma unroll
        for (int cb = 0; cb < 16; ++cb)
            bfr[cb] = *(const bf16x8*)&xs[(cb * 16 + l16) * CIp + ks * 32 + lq * 8];
#pragma unroll
        for (int dt = 0; dt < 4; ++dt) {
#pragma unroll
            for (int nb = 0; nb < 16; ++nb) {
                int cb = nb + (dt - 1) * 2;
                if (cb >= 0 && cb < 16)
                    acc[nb] = __builtin_amdgcn_mfma_f32_16x16x32_bf16(
                        afr[dt], bfr[cb], acc[nb], 0, 0, 0);
            }
        }
    }

    // ---- epilogue: BN + ReLU (+ pool) ----
    // thread's 4 co rows: co = co_base + wv*16 + lq*4 + j
    float sc[4], c2[4];
#pragma unroll
    for (int j = 0; j < 4; ++j) {
        int co = co_base + wv * 16 + lq * 4 + j;
        float scv = gg[co] / sqrtf(vv[co] + 1e-5f);
        sc[j] = scv;
        c2[j] = (bb[co] - mm[co]) * scv + be[co];
    }

    if (POOL) {
#pragma unroll
        for (int nbp = 0; nbp < 8; ++nbp) {       // t = nbp
#pragma unroll
            for (int j = 0; j < 4; ++j) {
                float v0 = fmaxf(acc[2 * nbp][j] * sc[j] + c2[j], 0.0f);
                float v1 = fmaxf(acc[2 * nbp + 1][j] * sc[j] + c2[j], 0.0f);
                float v = fmaxf(v0, v1);
#pragma unroll
                for (int off = 1; off < 16; off <<= 1)
                    v = fmaxf(v, __shfl_xor(v, off));
                if (l16 == 0) {
                    int co = co_base + wv * 16 + lq * 4 + j;
                    outPool[((size_t)(b * T_ + nbp) * 128 + co) * S_ + s] = v;
                }
            }
        }
    } else {
#pragma unroll
        for (int nb = 0; nb < 16; ++nb) {
            int col = nb * 16 + l16;
            short4v pk;
#pragma unroll
            for (int j = 0; j < 4; ++j)
                pk[j] = f2bf(fmaxf(acc[nb][j] * sc[j] + c2[j], 0.0f));
            *(short4v*)&actOut[(((size_t)b * S_ + s) * 256 + col) * 64 + wv * 16 + lq * 4] = pk;
        }
    }
}

// ---------------------------------------------------------------------------
extern "C" void kernel_launch(void* const* d_in, const int* in_sizes, int n_in,
                              void* d_out, int out_size, void* d_ws, size_t ws_size,
                              hipStream_t stream)
{
    (void)in_sizes; (void)n_in; (void)out_size; (void)ws_size;
    const float* xyz    = (const float*)d_in[0];
    const float* points = (const float*)d_in[1];
    const float* w0 = (const float*)d_in[2];
    const float* b0 = (const float*)d_in[3];
    const float* g0 = (const float*)d_in[4];
    const float* be0 = (const float*)d_in[5];
    const float* m0 = (const float*)d_in[6];
    const float* v0 = (const float*)d_in[7];
    const float* w1 = (const float*)d_in[8];
    const float* b1 = (const float*)d_in[9];
    const float* g1 = (const float*)d_in[10];
    const float* be1 = (const float*)d_in[11];
    const float* m1 = (const float*)d_in[12];
    const float* v1 = (const float*)d_in[13];
    const float* w2 = (const float*)d_in[14];
    const float* b2 = (const float*)d_in[15];
    const float* g2 = (const float*)d_in[16];
    const float* be2 = (const float*)d_in[17];
    const float* m2 = (const float*)d_in[18];
    const float* v2 = (const float*)d_in[19];

    float* out = (float*)d_out;
    char* ws = (char*)d_ws;
    int*   fidx = (int*)ws;                                   // 4 KB
    int*   gidx = (int*)(ws + 4096);                          // 1 MB
    float* nxyz = (float*)(ws + 4096 + 16 * 512 * 32 * 4);    // 96 KB
    short* actA = (short*)(ws + (size_t)(2 * 1024 * 1024));           // 32 MB bf16
    short* actB = (short*)(ws + (size_t)(2 * 1024 * 1024) + 67108864);// 32 MB bf16

    fps_kernel<<<B_, 64, 0, stream>>>(xyz, fidx);
    ballquery_kernel<<<dim3(S_, B_ * T_), 64, 0, stream>>>(xyz, fidx, gidx, nxyz, out);

    conv_mfma<67, 104, 3, true, false><<<dim3(S_, B_, 1), 256, 0, stream>>>(
        nullptr, xyz, points, gidx, nxyz, w0, b0, g0, be0, m0, v0, actA, nullptr);
    conv_mfma<64, 72, 2, false, false><<<dim3(S_, B_, 1), 256, 0, stream>>>(
        actA, nullptr, nullptr, nullptr, nullptr, w1, b1, g1, be1, m1, v1, actB, nullptr);
    conv_mfma<64, 72, 2, false, true><<<dim3(S_, B_, 2), 256, 0, stream>>>(
        actB, nullptr, nullptr, nullptr, nullptr, w2, b2, g2, be2, m2, v2, nullptr,
        out + (size_t)B_ * T_ * 3 * S_);
}

// Round 5
// 551.117 us; speedup vs baseline: 1.6379x; 1.0888x over previous
//
#include <hip/hip_runtime.h>
#include <math.h>

#define NPTS 1024
#define S_   512
#define T_   8
#define K_   32
#define B_   2

typedef short bf16x8 __attribute__((ext_vector_type(8)));
typedef short short4v __attribute__((ext_vector_type(4)));
typedef float f32x4 __attribute__((ext_vector_type(4)));

static __device__ __forceinline__ short f2bf(float f) {
    unsigned u = __float_as_uint(f);
    unsigned r = (u + 0x7FFFu + ((u >> 16) & 1u)) >> 16;   // RNE
    return (short)r;
}

// ---- DPP wave-64 max reduction helpers (result valid in lane 63) ----------
template <int CTRL>
static __device__ __forceinline__ float dppmaxf(float x) {
    int mv = __builtin_amdgcn_update_dpp(0, __float_as_int(x), CTRL, 0xF, 0xF, true);
    return fmaxf(x, __int_as_float(mv));
}
template <int CTRL>
static __device__ __forceinline__ int dppmaxi(int x) {
    int mv = __builtin_amdgcn_update_dpp(0, x, CTRL, 0xF, 0xF, true);
    return (x > mv) ? x : mv;
}
// full-wave max; returns lane-63 value broadcast via readlane (as bits)
static __device__ __forceinline__ int wavemax_bits_f(float x) {
    x = dppmaxf<0x111>(x); x = dppmaxf<0x112>(x);
    x = dppmaxf<0x114>(x); x = dppmaxf<0x118>(x);
    x = dppmaxf<0x142>(x); x = dppmaxf<0x143>(x);
    return __builtin_amdgcn_readlane(__float_as_int(x), 63);
}
static __device__ __forceinline__ int wavemax_i(int x) {
    x = dppmaxi<0x111>(x); x = dppmaxi<0x112>(x);
    x = dppmaxi<0x114>(x); x = dppmaxi<0x118>(x);
    x = dppmaxi<0x142>(x); x = dppmaxi<0x143>(x);
    return __builtin_amdgcn_readlane(x, 63);
}

// ---------------------------------------------------------------------------
// Kernel 1: farthest point sampling, DPP-reduction version (HW-verified r3).
// ---------------------------------------------------------------------------
__global__ void fps_kernel(const float* __restrict__ xyz, int* __restrict__ fidx)
{
    int b    = blockIdx.x;
    int lane = threadIdx.x;
    __shared__ float4 sc[NPTS];
    const float* bx = xyz + (size_t)b * (T_ * 3 * NPTS);   // frame 0 of batch b
    float px[16], py[16], pz[16], mind[16];
#pragma unroll
    for (int j = 0; j < 16; ++j) {
        int n = j * 64 + lane;
        float x = bx[n], y = bx[NPTS + n], z = bx[2 * NPTS + n];
        px[j] = x; py[j] = y; pz[j] = z;
        sc[n] = make_float4(x, y, z, 0.0f);
        mind[j] = 1e10f;
    }
    __syncthreads();
    int far = 0;
    for (int it = 0; it < S_; ++it) {
        if (lane == 0) fidx[b * S_ + it] = far;
        float4 c = sc[far];
#pragma unroll
        for (int j = 0; j < 16; ++j) {
            float dx = __fsub_rn(px[j], c.x);
            float dy = __fsub_rn(py[j], c.y);
            float dz = __fsub_rn(pz[j], c.z);
            float d  = __fmaf_rn(dz, dz, __fmaf_rn(dy, dy, __fmul_rn(dx, dx)));
            mind[j] = fminf(mind[j], d);
        }
        // per-lane tree max over 16
        float t8[8], t4[4], t2[2];
#pragma unroll
        for (int j = 0; j < 8; ++j) t8[j] = fmaxf(mind[j], mind[j + 8]);
#pragma unroll
        for (int j = 0; j < 4; ++j) t4[j] = fmaxf(t8[j], t8[j + 4]);
        t2[0] = fmaxf(t4[0], t4[2]); t2[1] = fmaxf(t4[1], t4[3]);
        float lmax = fmaxf(t2[0], t2[1]);
        unsigned maxb = (unsigned)wavemax_bits_f(lmax);
        // per-lane smallest j with bits == maxb (64 = none)
        int cj[16];
#pragma unroll
        for (int j = 0; j < 16; ++j)
            cj[j] = (__float_as_uint(mind[j]) == maxb) ? j : 64;
        int m8[8], m4[4], m2[2];
#pragma unroll
        for (int j = 0; j < 8; ++j) m8[j] = min(cj[j], cj[j + 8]);
#pragma unroll
        for (int j = 0; j < 4; ++j) m4[j] = min(m8[j], m8[j + 4]);
        m2[0] = min(m4[0], m4[2]); m2[1] = min(m4[1], m4[3]);
        int minj = min(m2[0], m2[1]);
        int kk = (minj < 64) ? (4095 - (minj * 64 + lane)) : 0;
        far = 4095 - wavemax_i(kk);
    }
}

// ---------------------------------------------------------------------------
// Kernel 1b: transpose points [bt][64][1024] f32 -> ptsT [bt][1024][64] bf16.
// ---------------------------------------------------------------------------
__global__ __launch_bounds__(256) void transpose_points(
    const float* __restrict__ pts, short* __restrict__ ptsT)
{
    int nt = blockIdx.x;      // 16 tiles of 64 points
    int bt = blockIdx.y;
    __shared__ float tile[64][65];
    int tid = threadIdx.x;
    for (int e = tid; e < 4096; e += 256) {
        int ci = e >> 6, nn = e & 63;
        tile[ci][nn] = pts[((size_t)bt * 64 + ci) * NPTS + nt * 64 + nn];
    }
    __syncthreads();
    for (int e = tid; e < 4096; e += 256) {
        int nn = e >> 6, ci = e & 63;
        ptsT[((size_t)bt * NPTS + nt * 64 + nn) * 64 + ci] = f2bf(tile[ci][nn]);
    }
}

// ---------------------------------------------------------------------------
// Kernel 2: ball query per (bt, s). 1 wave per block (unchanged).
// ---------------------------------------------------------------------------
__global__ void ballquery_kernel(const float* __restrict__ xyz,
                                 const int* __restrict__ fidx,
                                 int* __restrict__ gidx,
                                 float* __restrict__ newxyz,
                                 float* __restrict__ out0)
{
    int s    = blockIdx.x;
    int bt   = blockIdx.y;
    int b    = bt >> 3;
    int lane = threadIdx.x;
    const float* bx = xyz + (size_t)bt * 3 * NPTS;
    int fid = fidx[b * S_ + s];
    float nx = bx[fid], ny = bx[NPTS + fid], nz = bx[2 * NPTS + fid];
    if (lane < 3) {
        float vv = (lane == 0) ? nx : ((lane == 1) ? ny : nz);
        out0[(bt * 3 + lane) * S_ + s]   = vv;   // [B,t,3,S]
        newxyz[(bt * S_ + s) * 3 + lane] = vv;
    }
    float A = __fmaf_rn(nz, nz, __fmaf_rn(ny, ny, __fmul_rn(nx, nx)));
    const float R2 = (float)(0.2 * 0.2);
    int* g = gidx + (size_t)(bt * S_ + s) * K_;
    int count = 0, firstIdx = -1;
    for (int j = 0; j < 16; ++j) {
        if (count >= K_) break;
        int n = j * 64 + lane;
        float x = bx[n], y = bx[NPTS + n], z = bx[2 * NPTS + n];
        float Bn = __fmaf_rn(z, z, __fmaf_rn(y, y, __fmul_rn(x, x)));
        float C  = __fmaf_rn(nz, z, __fmaf_rn(ny, y, __fmul_rn(nx, x)));
        float sq = __fsub_rn(__fadd_rn(A, Bn), __fmul_rn(2.0f, C));
        bool valid = !(sq > R2);
        unsigned long long mb = __ballot(valid);
        if (valid) {
            int pos = count + __popcll(mb & ((1ull << lane) - 1ull));
            if (pos < K_) g[pos] = n;
        }
        if (firstIdx < 0 && mb) firstIdx = j * 64 + (__ffsll((long long)mb) - 1);
        count += __popcll(mb);
    }
    if (count < K_) {
        for (int p = count + lane; p < K_; p += 64) g[p] = firstIdx;
    }
}

// ---------------------------------------------------------------------------
// MFMA conv (round-2-verified math). GATHER reads bf16 rows from ptsT;
// layer-1 channel order is [points 64][gxyz 3][pad], weights permuted to match.
// ---------------------------------------------------------------------------
template <int CI, int CIp, int NK, bool GATHER, bool POOL>
__global__ __launch_bounds__(256) void conv_mfma(
    const short* __restrict__ actIn,
    const float* __restrict__ xyz, const short* __restrict__ ptsT,
    const int* __restrict__ gidx, const float* __restrict__ newxyz,
    const float* __restrict__ w,  const float* __restrict__ bb,
    const float* __restrict__ gg, const float* __restrict__ be,
    const float* __restrict__ mm, const float* __restrict__ vv,
    short* __restrict__ actOut, float* __restrict__ outPool)
{
    __shared__ __align__(16) short wsh[4 * 64 * CIp];
    __shared__ __align__(16) short xs[256 * CIp];
    int s = blockIdx.x, b = blockIdx.y;
    int co_base = blockIdx.z * 64;
    int tid = threadIdx.x;

    // ---- stage weights (fp32 -> bf16), layout [dt][co][ci'], zero-pad ----
    for (int e = tid; e < 4 * 64 * CIp; e += 256) {
        int dt = e / (64 * CIp);
        int rem = e - dt * (64 * CIp);
        int co = rem / CIp;
        int ci = rem - co * CIp;
        float val = 0.0f;
        if (GATHER) {
            int cref = (ci < 64) ? (ci + 3) : ((ci < 67) ? (ci - 64) : -1);
            if (cref >= 0)
                val = w[(((size_t)(co_base + co)) * CI + cref) * 4 + dt];
        } else {
            if (ci < CI)
                val = w[(((size_t)(co_base + co)) * CI + ci) * 4 + dt];
        }
        wsh[e] = f2bf(val);
    }

    // ---- stage x tile: xs[col][ci'] bf16, col = t*32 + k ----
    {
        int col = tid;
        short* xrow = &xs[col * CIp];
        if (GATHER) {
            int k = col & 31, tt = col >> 5;
            int bt = b * T_ + tt;
            int idx = gidx[((size_t)bt * S_ + s) * K_ + k];
            const short* prow = ptsT + ((size_t)bt * NPTS + idx) * 64;
#pragma unroll
            for (int c = 0; c < 8; ++c)   // 64 bf16 point channels
                ((int4*)xrow)[c] = ((const int4*)prow)[c];
            const float* nxp = &newxyz[((size_t)bt * S_ + s) * 3];
#pragma unroll
            for (int ci = 0; ci < 3; ++ci)
                xrow[64 + ci] = f2bf(xyz[(size_t)(bt * 3 + ci) * NPTS + idx] - nxp[ci]);
            for (int ci = 67; ci < CIp; ++ci) xrow[ci] = 0;
        } else {
            const short* src = actIn + (((size_t)b * S_ + s) * 256 + col) * 64;
#pragma unroll
            for (int c = 0; c < 8; ++c)   // 8 x 16B = 64 bf16 channels
                ((int4*)xrow)[c] = ((const int4*)src)[c];
            for (int ci = 64; ci < CIp; ++ci) xrow[ci] = 0;
        }
    }
    __syncthreads();

    int lane = tid & 63;
    int wv   = tid >> 6;          // wave id 0..3 -> co stripe
    int l16  = lane & 15;
    int lq   = lane >> 4;

    f32x4 acc[16];
#pragma unroll
    for (int nb = 0; nb < 16; ++nb) acc[nb] = (f32x4){0.f, 0.f, 0.f, 0.f};

#pragma unroll
    for (int ks = 0; ks < NK; ++ks) {
        bf16x8 afr[4];
#pragma unroll
        for (int dt = 0; dt < 4; ++dt)
            afr[dt] = *(const bf16x8*)&wsh[(dt * 64 + wv * 16 + l16) * CIp + ks * 32 + lq * 8];
        bf16x8 bfr[16];
#pragma unroll
        for (int cb = 0; cb < 16; ++cb)
            bfr[cb] = *(const bf16x8*)&xs[(cb * 16 + l16) * CIp + ks * 32 + lq * 8];
#pragma unroll
        for (int dt = 0; dt < 4; ++dt) {
#pragma unroll
            for (int nb = 0; nb < 16; ++nb) {
                int cb = nb + (dt - 1) * 2;
                if (cb >= 0 && cb < 16)
                    acc[nb] = __builtin_amdgcn_mfma_f32_16x16x32_bf16(
                        afr[dt], bfr[cb], acc[nb], 0, 0, 0);
            }
        }
    }

    // ---- epilogue: BN + ReLU (+ pool) ----
    float sc[4], c2[4];
#pragma unroll
    for (int j = 0; j < 4; ++j) {
        int co = co_base + wv * 16 + lq * 4 + j;
        float scv = gg[co] / sqrtf(vv[co] + 1e-5f);
        sc[j] = scv;
        c2[j] = (bb[co] - mm[co]) * scv + be[co];
    }

    if (POOL) {
#pragma unroll
        for (int nbp = 0; nbp < 8; ++nbp) {       // t = nbp
#pragma unroll
            for (int j = 0; j < 4; ++j) {
                float v0 = fmaxf(acc[2 * nbp][j] * sc[j] + c2[j], 0.0f);
                float v1 = fmaxf(acc[2 * nbp + 1][j] * sc[j] + c2[j], 0.0f);
                float v = fmaxf(v0, v1);
#pragma unroll
                for (int off = 1; off < 16; off <<= 1)
                    v = fmaxf(v, __shfl_xor(v, off));
                if (l16 == 0) {
                    int co = co_base + wv * 16 + lq * 4 + j;
                    outPool[((size_t)(b * T_ + nbp) * 128 + co) * S_ + s] = v;
                }
            }
        }
    } else {
#pragma unroll
        for (int nb = 0; nb < 16; ++nb) {
            int col = nb * 16 + l16;
            short4v pk;
#pragma unroll
            for (int j = 0; j < 4; ++j)
                pk[j] = f2bf(fmaxf(acc[nb][j] * sc[j] + c2[j], 0.0f));
            *(short4v*)&actOut[(((size_t)b * S_ + s) * 256 + col) * 64 + wv * 16 + lq * 4] = pk;
        }
    }
}

// ---------------------------------------------------------------------------
extern "C" void kernel_launch(void* const* d_in, const int* in_sizes, int n_in,
                              void* d_out, int out_size, void* d_ws, size_t ws_size,
                              hipStream_t stream)
{
    (void)in_sizes; (void)n_in; (void)out_size; (void)ws_size;
    const float* xyz    = (const float*)d_in[0];
    const float* points = (const float*)d_in[1];
    const float* w0 = (const float*)d_in[2];
    const float* b0 = (const float*)d_in[3];
    const float* g0 = (const float*)d_in[4];
    const float* be0 = (const float*)d_in[5];
    const float* m0 = (const float*)d_in[6];
    const float* v0 = (const float*)d_in[7];
    const float* w1 = (const float*)d_in[8];
    const float* b1 = (const float*)d_in[9];
    const float* g1 = (const float*)d_in[10];
    const float* be1 = (const float*)d_in[11];
    const float* m1 = (const float*)d_in[12];
    const float* v1 = (const float*)d_in[13];
    const float* w2 = (const float*)d_in[14];
    const float* b2 = (const float*)d_in[15];
    const float* g2 = (const float*)d_in[16];
    const float* be2 = (const float*)d_in[17];
    const float* m2 = (const float*)d_in[18];
    const float* v2 = (const float*)d_in[19];

    float* out = (float*)d_out;
    char* ws = (char*)d_ws;
    // workspace map (sizes exact):
    //   fidx  @ 0        : 2*512*4            =   4 KB
    //   gidx  @ 4 KB     : 16*512*32*4        =   1 MB
    //   nxyz  @ ~1.05 MB : 16*512*3*4         =  96 KB
    //   ptsT  @ 4  MB    : 16*1024*64*2       = 2.1 MB
    //   actA  @ 8  MB    : 2*512*256*64*2     = 33.6 MB  (ends 41.6 MB)
    //   actB  @ 44 MB    : 33.6 MB            (ends 77.6 MB; r2 proved >=98 MB ok)
    int*   fidx = (int*)ws;
    int*   gidx = (int*)(ws + 4096);
    float* nxyz = (float*)(ws + 4096 + 16 * 512 * 32 * 4);
    short* ptsT = (short*)(ws + (size_t)(4  * 1024 * 1024));
    short* actA = (short*)(ws + (size_t)(8  * 1024 * 1024));
    short* actB = (short*)(ws + (size_t)(44 * 1024 * 1024));

    transpose_points<<<dim3(16, B_ * T_), 256, 0, stream>>>(points, ptsT);
    fps_kernel<<<B_, 64, 0, stream>>>(xyz, fidx);
    ballquery_kernel<<<dim3(S_, B_ * T_), 64, 0, stream>>>(xyz, fidx, gidx, nxyz, out);

    conv_mfma<67, 104, 3, true, false><<<dim3(S_, B_, 1), 256, 0, stream>>>(
        nullptr, xyz, ptsT, gidx, nxyz, w0, b0, g0, be0, m0, v0, actA, nullptr);
    conv_mfma<64, 72, 2, false, false><<<dim3(S_, B_, 1), 256, 0, stream>>>(
        actA, nullptr, nullptr, nullptr, nullptr, w1, b1, g1, be1, m1, v1, actB, nullptr);
    conv_mfma<64, 72, 2, false, true><<<dim3(S_, B_, 2), 256, 0, stream>>>(
        actB, nullptr, nullptr, nullptr, nullptr, w2, b2, g2, be2, m2, v2, nullptr,
        out + (size_t)B_ * T_ * 3 * S_);
}